// Round 8
// baseline (1040.656 us; speedup 1.0000x reference)
//
#include <hip/hip_runtime.h>
#include <hip/hip_bf16.h>

#define B_ 64
#define L_ 512
#define H_ 1024
#define A_ 1024

typedef short bf16x8 __attribute__((ext_vector_type(8)));
typedef float f32x4 __attribute__((ext_vector_type(4)));

__device__ __forceinline__ void gld16(const void* g, void* l) {
  __builtin_amdgcn_global_load_lds((const __attribute__((address_space(1))) void*)g,
                                   (__attribute__((address_space(3))) void*)l, 16, 0, 0);
}

// f32 -> bf16 RNE bit trick (cold paths)
__device__ __forceinline__ unsigned short f2bf(float f) {
  unsigned u = __builtin_bit_cast(unsigned, f);
  u = (u + 0x7fffu + ((u >> 16) & 1u)) >> 16;
  return (unsigned short)u;
}

// hot-path cast: compiler fuses pairs into v_cvt_pk_bf16_f32
__device__ __forceinline__ unsigned short cvtbf(float f) {
  __hip_bfloat16 b = __float2bfloat16(f);
  return __builtin_bit_cast(unsigned short, b);
}

// tanh(x) = 1 - 2/(exp(2x)+1) with fast rcp (~1ulp, invisible in bf16)
__device__ __forceinline__ float fast_tanh(float x) {
  float e = __expf(2.f * x);
  float r = __builtin_amdgcn_rcpf(e + 1.f);
  return __builtin_fmaf(-2.f, r, 1.f);
}

// ---------- K-1: Xb = bf16(concat(Xlt, Xrt)), streaming ----------
__global__ __launch_bounds__(256) void cvt_kernel(const float* __restrict__ lt,
                                                  const float* __restrict__ rt,
                                                  unsigned short* __restrict__ xb) {
  const size_t NC = (size_t)B_ * L_ * H_ / 8;  // chunks per tensor
  size_t stride = (size_t)gridDim.x * blockDim.x;
  for (size_t c = (size_t)blockIdx.x * blockDim.x + threadIdx.x; c < 2 * NC; c += stride) {
    const float* src = (c < NC) ? (lt + c * 8) : (rt + (c - NC) * 8);
    float4 v0 = ((const float4*)src)[0];
    float4 v1 = ((const float4*)src)[1];
    bf16x8 o;
    o[0] = (short)cvtbf(v0.x); o[1] = (short)cvtbf(v0.y);
    o[2] = (short)cvtbf(v0.z); o[3] = (short)cvtbf(v0.w);
    o[4] = (short)cvtbf(v1.x); o[5] = (short)cvtbf(v1.y);
    o[6] = (short)cvtbf(v1.z); o[7] = (short)cvtbf(v1.w);
    *(bf16x8*)(xb + c * 8) = o;
  }
}

// ---------- K0: Wt[a][h] = bf16(W[h][a]) ----------
__global__ __launch_bounds__(256) void wtrans_kernel(const float* __restrict__ W,
                                                     unsigned short* __restrict__ Wt) {
  __shared__ float tile[32][33];
  int tx = threadIdx.x & 31, ty = threadIdx.x >> 5;  // 32 x 8
  int a0 = (blockIdx.x & 31) << 5, h0 = (blockIdx.x >> 5) << 5;
#pragma unroll
  for (int i = 0; i < 4; ++i) {
    int h = ty + i * 8;
    tile[h][tx] = W[(size_t)(h0 + h) * A_ + a0 + tx];
  }
  __syncthreads();
#pragma unroll
  for (int i = 0; i < 4; ++i) {
    int a = ty + i * 8;
    Wt[(size_t)(a0 + a) * H_ + h0 + tx] = f2bf(tile[tx][a]);
  }
}

// ---------- K1: 256x256 dbuf proj (64KB LDS -> 2 blocks/CU): ----------
// Pb = bf16(tanh(Xb @ Wt^T) [*diag]). 512 threads = 8 waves (2Mx4N), BK=32.
// Schedule per tile: STAGE(next) -> vmcnt(4) [drains CURRENT tile's loads,
// issued one full compute phase earlier] -> s_barrier -> compute -> s_barrier
// (protects buffer reuse). Cross-block TLP (2 blocks/CU) hides the convoys.
// Swizzle (64B rows, 4 chunks): LDS slot s of row r holds global chunk
// s ^ ((r>>1)&3) -> every 8-lane phase covers all 32 banks (0 conflicts).
__global__ __launch_bounds__(512, 4) void proj8_kernel(
    const unsigned short* __restrict__ Xb, const unsigned short* __restrict__ Wt,
    const float* __restrict__ diag, unsigned short* __restrict__ Pb) {
  __shared__ unsigned short As2[2][256 * 32];  // 2 x 16 KB
  __shared__ unsigned short Bs2[2][256 * 32];  // 2 x 16 KB
  int t = threadIdx.x;                 // 0..511
  int lane = t & 63, wave = t >> 6;
  int wr = wave >> 2, wcn = wave & 3;  // wave grid 2M x 4N, each 128x64 out
  int l15 = lane & 15, l4 = lane >> 4;

  // XCD swizzle: each XCD runs 4 consecutive N-tiles of one M-tile
  int bid = (int)blockIdx.x;           // 1024 blocks
  int x = bid & 7, k = bid >> 3;       // k in [0,128)
  int mt = x + 8 * (k >> 2);           // [0,256)
  int nt = k & 3;                      // [0,4)
  int mrow0 = mt << 8;
  int ncol0 = nt << 8;
  int isLt = (mt < 128);

  // staging: issue i covers chunk ci = i*512 + t -> row = ci>>2, slot c = ci&3
  const unsigned short* asrc[2];
  const unsigned short* bsrc[2];
#pragma unroll
  for (int i = 0; i < 2; ++i) {
    int ci = i * 512 + t;
    int r = ci >> 2, c = ci & 3;
    int sc = (c ^ ((r >> 1) & 3)) << 3;  // pre-swizzled source chunk
    asrc[i] = Xb + (size_t)(mrow0 + r) * H_ + sc;
    bsrc[i] = Wt + (size_t)(ncol0 + r) * H_ + sc;
  }

#define STAGE2(buf, kt_)                                        \
  {                                                             \
    int ko = (kt_) * 32;                                        \
    gld16(asrc[0] + ko, &As2[buf][t * 8]);                      \
    gld16(asrc[1] + ko, &As2[buf][(512 + t) * 8]);              \
    gld16(bsrc[0] + ko, &Bs2[buf][t * 8]);                      \
    gld16(bsrc[1] + ko, &Bs2[buf][(512 + t) * 8]);              \
  }

  f32x4 acc[8][4] = {};
  // fragment-read swizzle: lane wants chunk l4 of row (..)*16+l15
  int rdsw = (l4 ^ ((l15 >> 1) & 3)) * 8;

  STAGE2(0, 0);
  for (int j = 0; j < 32; ++j) {
    if (j < 31) {
      STAGE2((j + 1) & 1, j + 1);
      asm volatile("s_waitcnt vmcnt(4)" ::: "memory");  // tile j ready; j+1 in flight
    } else {
      asm volatile("s_waitcnt vmcnt(0)" ::: "memory");
    }
    asm volatile("s_barrier" ::: "memory");

    const unsigned short* Ac = As2[j & 1];
    const unsigned short* Bc = Bs2[j & 1];
    bf16x8 bq[4];
#pragma unroll
    for (int ni = 0; ni < 4; ++ni)
      bq[ni] = *(const bf16x8*)&Bc[(wcn * 64 + ni * 16 + l15) * 32 + rdsw];
#pragma unroll
    for (int ph = 0; ph < 4; ++ph) {
      bf16x8 aq0 = *(const bf16x8*)&Ac[(wr * 128 + (ph * 2) * 16 + l15) * 32 + rdsw];
      bf16x8 aq1 = *(const bf16x8*)&Ac[(wr * 128 + (ph * 2 + 1) * 16 + l15) * 32 + rdsw];
      __builtin_amdgcn_s_setprio(1);
#pragma unroll
      for (int ni = 0; ni < 4; ++ni) {
        acc[ph * 2][ni] = __builtin_amdgcn_mfma_f32_16x16x32_bf16(
            aq0, bq[ni], acc[ph * 2][ni], 0, 0, 0);
        acc[ph * 2 + 1][ni] = __builtin_amdgcn_mfma_f32_16x16x32_bf16(
            aq1, bq[ni], acc[ph * 2 + 1][ni], 0, 0, 0);
      }
      __builtin_amdgcn_s_setprio(0);
    }
    asm volatile("s_barrier" ::: "memory");  // buffer-reuse guard
  }
#undef STAGE2

#pragma unroll
  for (int mi = 0; mi < 8; ++mi) {
#pragma unroll
    for (int ni = 0; ni < 4; ++ni) {
      int col = ncol0 + wcn * 64 + ni * 16 + l15;
      float d = isLt ? diag[col] : 1.0f;
#pragma unroll
      for (int rr = 0; rr < 4; ++rr) {
        int row = mrow0 + wr * 128 + mi * 16 + l4 * 4 + rr;
        Pb[(size_t)row * A_ + col] = f2bf(fast_tanh(acc[mi][ni][rr]) * d);
      }
    }
  }
}

// ---------- K2: scores[b][l][r] = (Plt[b,l,:] . Prt[b,r,:]) * ml * mr ----------
__global__ __launch_bounds__(256) void score_kernel(
    const unsigned short* __restrict__ Plt, const unsigned short* __restrict__ Prt,
    const float* __restrict__ mask_lt, const float* __restrict__ mask_rt,
    float* __restrict__ out) {
  __shared__ unsigned short As[128 * 64];
  __shared__ unsigned short Bs[128 * 64];
  int t = threadIdx.x;
  int lane = t & 63, wave = t >> 6;
  int wr = wave >> 1, wc = wave & 1;
  int l15 = lane & 15, l4 = lane >> 4;

  int bid = (int)blockIdx.x;                 // 1024 blocks
  int x = bid & 7, k = bid >> 3;             // k in [0,128)
  int atile = x + 8 * (k >> 2);              // [0,256)
  int b = atile >> 2, tm = atile & 3, tn = k & 3;

  const unsigned short* Abase = Plt + (size_t)b * L_ * A_ + (size_t)(tm * 128) * A_;
  const unsigned short* Bbase = Prt + (size_t)b * L_ * A_ + (size_t)(tn * 128) * A_;

  const unsigned short* asrc[4];
  const unsigned short* bsrc[4];
  int dst[4];
#pragma unroll
  for (int i = 0; i < 4; ++i) {
    int c = i * 256 + t;
    int r = c >> 3, kc = c & 7;
    int sc = (kc ^ (r & 7)) * 8;
    asrc[i] = &Abase[(size_t)r * A_ + sc];
    bsrc[i] = &Bbase[(size_t)r * A_ + sc];
    dst[i] = c * 8;
  }
  int swz0 = ((0 * 4 + l4) ^ (l15 & 7)) * 8;
  int swz1 = ((1 * 4 + l4) ^ (l15 & 7)) * 8;

  f32x4 acc[4][4] = {};
  for (int kt = 0; kt < A_ / 64; ++kt) {
    int k0 = kt * 64;
    __syncthreads();
#pragma unroll
    for (int i = 0; i < 4; ++i) {
      gld16(asrc[i] + k0, &As[dst[i]]);
      gld16(bsrc[i] + k0, &Bs[dst[i]]);
    }
    __syncthreads();
#pragma unroll
    for (int kk = 0; kk < 2; ++kk) {
      int sw = kk ? swz1 : swz0;
      bf16x8 aq[4], bq[4];
#pragma unroll
      for (int mi = 0; mi < 4; ++mi)
        aq[mi] = *(const bf16x8*)&As[(wr * 64 + mi * 16 + l15) * 64 + sw];
#pragma unroll
      for (int ni = 0; ni < 4; ++ni)
        bq[ni] = *(const bf16x8*)&Bs[(wc * 64 + ni * 16 + l15) * 64 + sw];
#pragma unroll
      for (int mi = 0; mi < 4; ++mi)
#pragma unroll
        for (int ni = 0; ni < 4; ++ni)
          acc[mi][ni] = __builtin_amdgcn_mfma_f32_16x16x32_bf16(aq[mi], bq[ni], acc[mi][ni], 0, 0, 0);
    }
  }
  const float* mlp = mask_lt + b * L_;
  const float* mrp = mask_rt + b * L_;
  float* obase = out + (size_t)b * L_ * L_;
#pragma unroll
  for (int mi = 0; mi < 4; ++mi) {
#pragma unroll
    for (int ni = 0; ni < 4; ++ni) {
      int col = tn * 128 + wc * 64 + ni * 16 + l15;
      float mr = mrp[col];
#pragma unroll
      for (int r = 0; r < 4; ++r) {
        int row = tm * 128 + wr * 64 + mi * 16 + l4 * 4 + r;
        obase[(size_t)row * L_ + col] = acc[mi][ni][r] * mlp[row] * mr;
      }
    }
  }
}

// ---------- K3: in-place row softmax over 512, then re-mask ----------
__global__ __launch_bounds__(256) void softmax_kernel(float* __restrict__ out,
                                                      const float* __restrict__ mask_lt,
                                                      const float* __restrict__ mask_rt) {
  int lane = threadIdx.x & 63, wave = threadIdx.x >> 6;
  int row = (int)blockIdx.x * 4 + wave;  // 0..32767
  int b = row >> 9;
  float* p = out + (size_t)row * L_;
  float4 v0 = *(const float4*)(p + lane * 8);
  float4 v1 = *(const float4*)(p + lane * 8 + 4);
  float m = fmaxf(fmaxf(fmaxf(v0.x, v0.y), fmaxf(v0.z, v0.w)),
                  fmaxf(fmaxf(v1.x, v1.y), fmaxf(v1.z, v1.w)));
#pragma unroll
  for (int off = 32; off; off >>= 1) m = fmaxf(m, __shfl_xor(m, off));
  float e0 = __expf(v0.x - m), e1 = __expf(v0.y - m), e2 = __expf(v0.z - m), e3 = __expf(v0.w - m);
  float e4 = __expf(v1.x - m), e5 = __expf(v1.y - m), e6 = __expf(v1.z - m), e7 = __expf(v1.w - m);
  float s = ((e0 + e1) + (e2 + e3)) + ((e4 + e5) + (e6 + e7));
#pragma unroll
  for (int off = 32; off; off >>= 1) s += __shfl_xor(s, off);
  float sc = (1.0f / s) * mask_lt[row];
  const float* mrp = mask_rt + (b << 9) + lane * 8;
  float4 mr0 = *(const float4*)mrp;
  float4 mr1 = *(const float4*)(mrp + 4);
  float4 o0 = make_float4(e0 * sc * mr0.x, e1 * sc * mr0.y, e2 * sc * mr0.z, e3 * sc * mr0.w);
  float4 o1 = make_float4(e4 * sc * mr1.x, e5 * sc * mr1.y, e6 * sc * mr1.z, e7 * sc * mr1.w);
  *(float4*)(p + lane * 8) = o0;
  *(float4*)(p + lane * 8 + 4) = o1;
}

extern "C" void kernel_launch(void* const* d_in, const int* in_sizes, int n_in,
                              void* d_out, int out_size, void* d_ws, size_t ws_size,
                              hipStream_t stream) {
  const float* reps_lt = (const float*)d_in[0];
  const float* reps_rt = (const float*)d_in[1];
  const float* mask_lt = (const float*)d_in[2];
  const float* mask_rt = (const float*)d_in[3];
  const float* attn_w1 = (const float*)d_in[4];
  const float* diag    = (const float*)d_in[5];
  float* out = (float*)d_out;

  unsigned short* wt  = (unsigned short*)d_ws;          // 2 MB
  unsigned short* pb  = wt + (size_t)H_ * A_;           // 128 MB
  unsigned short* xb  = pb + (size_t)B_ * L_ * A_ * 2;  // 128 MB
  unsigned short* plt = pb;
  unsigned short* prt = pb + (size_t)B_ * L_ * A_;

  hipLaunchKernelGGL(wtrans_kernel, dim3(1024), dim3(256), 0, stream, attn_w1, wt);
  hipLaunchKernelGGL(cvt_kernel, dim3(8192), dim3(256), 0, stream,
                     reps_lt, reps_rt, xb);
  hipLaunchKernelGGL(proj8_kernel, dim3(1024), dim3(512), 0, stream,
                     xb, wt, diag, pb);
  hipLaunchKernelGGL(score_kernel, dim3(1024), dim3(256), 0, stream,
                     plt, prt, mask_lt, mask_rt, out);
  hipLaunchKernelGGL(softmax_kernel, dim3(8192), dim3(256), 0, stream,
                     out, mask_lt, mask_rt);
}

// Round 9
// 320.121 us; speedup vs baseline: 3.2508x; 3.2508x over previous
//
#include <hip/hip_runtime.h>
#include <hip/hip_bf16.h>

#define B_ 64
#define L_ 512
#define H_ 1024
#define A_ 1024

typedef short bf16x8 __attribute__((ext_vector_type(8)));
typedef float f32x4 __attribute__((ext_vector_type(4)));

__device__ __forceinline__ void gld16(const void* g, void* l) {
  __builtin_amdgcn_global_load_lds((const __attribute__((address_space(1))) void*)g,
                                   (__attribute__((address_space(3))) void*)l, 16, 0, 0);
}

// f32 -> bf16 RNE bit trick (cold paths)
__device__ __forceinline__ unsigned short f2bf(float f) {
  unsigned u = __builtin_bit_cast(unsigned, f);
  u = (u + 0x7fffu + ((u >> 16) & 1u)) >> 16;
  return (unsigned short)u;
}

// hot-path cast: compiler fuses pairs into v_cvt_pk_bf16_f32
__device__ __forceinline__ unsigned short cvtbf(float f) {
  __hip_bfloat16 b = __float2bfloat16(f);
  return __builtin_bit_cast(unsigned short, b);
}

// tanh(x) = 1 - 2/(exp(2x)+1) with fast rcp (~1ulp, invisible in bf16)
__device__ __forceinline__ float fast_tanh(float x) {
  float e = __expf(2.f * x);
  float r = __builtin_amdgcn_rcpf(e + 1.f);
  return __builtin_fmaf(-2.f, r, 1.f);
}

// ---------- K-1: Xb = bf16(concat(Xlt, Xrt)), streaming ----------
__global__ __launch_bounds__(256) void cvt_kernel(const float* __restrict__ lt,
                                                  const float* __restrict__ rt,
                                                  unsigned short* __restrict__ xb) {
  const size_t NC = (size_t)B_ * L_ * H_ / 8;  // chunks per tensor
  size_t stride = (size_t)gridDim.x * blockDim.x;
  for (size_t c = (size_t)blockIdx.x * blockDim.x + threadIdx.x; c < 2 * NC; c += stride) {
    const float* src = (c < NC) ? (lt + c * 8) : (rt + (c - NC) * 8);
    float4 v0 = ((const float4*)src)[0];
    float4 v1 = ((const float4*)src)[1];
    bf16x8 o;
    o[0] = (short)cvtbf(v0.x); o[1] = (short)cvtbf(v0.y);
    o[2] = (short)cvtbf(v0.z); o[3] = (short)cvtbf(v0.w);
    o[4] = (short)cvtbf(v1.x); o[5] = (short)cvtbf(v1.y);
    o[6] = (short)cvtbf(v1.z); o[7] = (short)cvtbf(v1.w);
    *(bf16x8*)(xb + c * 8) = o;
  }
}

// ---------- K0: Wt[a][h] = bf16(W[h][a]) ----------
__global__ __launch_bounds__(256) void wtrans_kernel(const float* __restrict__ W,
                                                     unsigned short* __restrict__ Wt) {
  __shared__ float tile[32][33];
  int tx = threadIdx.x & 31, ty = threadIdx.x >> 5;  // 32 x 8
  int a0 = (blockIdx.x & 31) << 5, h0 = (blockIdx.x >> 5) << 5;
#pragma unroll
  for (int i = 0; i < 4; ++i) {
    int h = ty + i * 8;
    tile[h][tx] = W[(size_t)(h0 + h) * A_ + a0 + tx];
  }
  __syncthreads();
#pragma unroll
  for (int i = 0; i < 4; ++i) {
    int a = ty + i * 8;
    Wt[(size_t)(a0 + a) * H_ + h0 + tx] = f2bf(tile[tx][a]);
  }
}

// ---------- K1: 128x256 dbuf proj, 2 blocks/CU: Pb = bf16(tanh(Xb@Wt^T)[*diag]) ----
// 512 threads = 8 waves (2M x 4N), each wave 64x64 out -> acc = 64 f32/lane,
// unified VGPR ~120 <= 128 cap from __launch_bounds__(512,4) -> 16 waves/CU.
// BK=32, dbuf LDS 48KB (2 blocks/CU by LDS too). Counted vmcnt(3): next tile's
// 3 loads stay in flight across compute. Swizzle (R8, PMC=0 conflicts):
// LDS slot s of row r holds global chunk s ^ ((r>>1)&3).
__global__ __launch_bounds__(512, 4) void proj8_kernel(
    const unsigned short* __restrict__ Xb, const unsigned short* __restrict__ Wt,
    const float* __restrict__ diag, unsigned short* __restrict__ Pb) {
  __shared__ unsigned short As2[2][128 * 32];  // 2 x 8 KB
  __shared__ unsigned short Bs2[2][256 * 32];  // 2 x 16 KB
  int t = threadIdx.x;                 // 0..511
  int lane = t & 63, wave = t >> 6;
  int wr = wave >> 2, wc = wave & 3;   // wave grid 2M x 4N, each 64x64 out
  int l15 = lane & 15, l4 = lane >> 4;

  // XCD swizzle: each XCD runs nt=0..3 consecutively for its mt panel
  int bid = (int)blockIdx.x;           // 2048 blocks
  int x = bid & 7, k = bid >> 3;       // k in [0,256)
  int mt = x + 8 * (k >> 2);           // [0,512)
  int nt = k & 3;                      // [0,4)
  int mrow0 = mt << 7;                 // 128-row panel
  int ncol0 = nt << 8;                 // 256-col panel
  int isLt = (mt < 256);

  // staging (3 gld16/thread/tile): A chunk t (r=t>>2,c=t&3); B chunks i*512+t
  int ra = t >> 2, ca = t & 3;
  const unsigned short* asrc = Xb + (size_t)(mrow0 + ra) * H_ + ((ca ^ ((ra >> 1) & 3)) << 3);
  const unsigned short* bsrc[2];
#pragma unroll
  for (int i = 0; i < 2; ++i) {
    int ci = i * 512 + t;
    int r = ci >> 2, c = ci & 3;
    bsrc[i] = Wt + (size_t)(ncol0 + r) * H_ + ((c ^ ((r >> 1) & 3)) << 3);
  }

#define STAGE(buf, kt_)                                         \
  {                                                             \
    int ko = (kt_) * 32;                                        \
    gld16(asrc + ko, &As2[buf][t * 8]);                         \
    gld16(bsrc[0] + ko, &Bs2[buf][t * 8]);                      \
    gld16(bsrc[1] + ko, &Bs2[buf][(512 + t) * 8]);              \
  }

  f32x4 acc[4][4] = {};
  int rdsw = (l4 ^ ((l15 >> 1) & 3)) * 8;  // fragment-read swizzled chunk

  STAGE(0, 0);
  for (int j = 0; j < 32; ++j) {
    if (j < 31) {
      STAGE((j + 1) & 1, j + 1);
      asm volatile("s_waitcnt vmcnt(3)" ::: "memory");  // tile j ready; j+1 in flight
    } else {
      asm volatile("s_waitcnt vmcnt(0)" ::: "memory");
    }
    asm volatile("s_barrier" ::: "memory");

    const unsigned short* Ac = As2[j & 1];
    const unsigned short* Bc = Bs2[j & 1];
    bf16x8 aq[4], bq[4];
#pragma unroll
    for (int mi = 0; mi < 4; ++mi)
      aq[mi] = *(const bf16x8*)&Ac[(wr * 64 + mi * 16 + l15) * 32 + rdsw];
#pragma unroll
    for (int ni = 0; ni < 4; ++ni)
      bq[ni] = *(const bf16x8*)&Bc[(wc * 64 + ni * 16 + l15) * 32 + rdsw];
    __builtin_amdgcn_s_setprio(1);
#pragma unroll
    for (int mi = 0; mi < 4; ++mi)
#pragma unroll
      for (int ni = 0; ni < 4; ++ni)
        acc[mi][ni] = __builtin_amdgcn_mfma_f32_16x16x32_bf16(aq[mi], bq[ni], acc[mi][ni], 0, 0, 0);
    __builtin_amdgcn_s_setprio(0);
    asm volatile("s_barrier" ::: "memory");  // buffer-reuse guard
  }
#undef STAGE

#pragma unroll
  for (int mi = 0; mi < 4; ++mi) {
#pragma unroll
    for (int ni = 0; ni < 4; ++ni) {
      int col = ncol0 + wc * 64 + ni * 16 + l15;
      float d = isLt ? diag[col] : 1.0f;
#pragma unroll
      for (int rr = 0; rr < 4; ++rr) {
        int row = mrow0 + wr * 64 + mi * 16 + l4 * 4 + rr;
        Pb[(size_t)row * A_ + col] = f2bf(fast_tanh(acc[mi][ni][rr]) * d);
      }
    }
  }
}

// ---------- K2: scores[b][l][r] = (Plt[b,l,:] . Prt[b,r,:]) * ml * mr ----------
__global__ __launch_bounds__(256) void score_kernel(
    const unsigned short* __restrict__ Plt, const unsigned short* __restrict__ Prt,
    const float* __restrict__ mask_lt, const float* __restrict__ mask_rt,
    float* __restrict__ out) {
  __shared__ unsigned short As[128 * 64];
  __shared__ unsigned short Bs[128 * 64];
  int t = threadIdx.x;
  int lane = t & 63, wave = t >> 6;
  int wr = wave >> 1, wc = wave & 1;
  int l15 = lane & 15, l4 = lane >> 4;

  int bid = (int)blockIdx.x;                 // 1024 blocks
  int x = bid & 7, k = bid >> 3;             // k in [0,128)
  int atile = x + 8 * (k >> 2);              // [0,256)
  int b = atile >> 2, tm = atile & 3, tn = k & 3;

  const unsigned short* Abase = Plt + (size_t)b * L_ * A_ + (size_t)(tm * 128) * A_;
  const unsigned short* Bbase = Prt + (size_t)b * L_ * A_ + (size_t)(tn * 128) * A_;

  const unsigned short* asrc[4];
  const unsigned short* bsrc[4];
  int dst[4];
#pragma unroll
  for (int i = 0; i < 4; ++i) {
    int c = i * 256 + t;
    int r = c >> 3, kc = c & 7;
    int sc = (kc ^ (r & 7)) * 8;
    asrc[i] = &Abase[(size_t)r * A_ + sc];
    bsrc[i] = &Bbase[(size_t)r * A_ + sc];
    dst[i] = c * 8;
  }
  int swz0 = ((0 * 4 + l4) ^ (l15 & 7)) * 8;
  int swz1 = ((1 * 4 + l4) ^ (l15 & 7)) * 8;

  f32x4 acc[4][4] = {};
  for (int kt = 0; kt < A_ / 64; ++kt) {
    int k0 = kt * 64;
    __syncthreads();
#pragma unroll
    for (int i = 0; i < 4; ++i) {
      gld16(asrc[i] + k0, &As[dst[i]]);
      gld16(bsrc[i] + k0, &Bs[dst[i]]);
    }
    __syncthreads();
#pragma unroll
    for (int kk = 0; kk < 2; ++kk) {
      int sw = kk ? swz1 : swz0;
      bf16x8 aq[4], bq[4];
#pragma unroll
      for (int mi = 0; mi < 4; ++mi)
        aq[mi] = *(const bf16x8*)&As[(wr * 64 + mi * 16 + l15) * 64 + sw];
#pragma unroll
      for (int ni = 0; ni < 4; ++ni)
        bq[ni] = *(const bf16x8*)&Bs[(wc * 64 + ni * 16 + l15) * 64 + sw];
#pragma unroll
      for (int mi = 0; mi < 4; ++mi)
#pragma unroll
        for (int ni = 0; ni < 4; ++ni)
          acc[mi][ni] = __builtin_amdgcn_mfma_f32_16x16x32_bf16(aq[mi], bq[ni], acc[mi][ni], 0, 0, 0);
    }
  }
  const float* mlp = mask_lt + b * L_;
  const float* mrp = mask_rt + b * L_;
  float* obase = out + (size_t)b * L_ * L_;
#pragma unroll
  for (int mi = 0; mi < 4; ++mi) {
#pragma unroll
    for (int ni = 0; ni < 4; ++ni) {
      int col = tn * 128 + wc * 64 + ni * 16 + l15;
      float mr = mrp[col];
#pragma unroll
      for (int r = 0; r < 4; ++r) {
        int row = tm * 128 + wr * 64 + mi * 16 + l4 * 4 + r;
        obase[(size_t)row * L_ + col] = acc[mi][ni][r] * mlp[row] * mr;
      }
    }
  }
}

// ---------- K3: in-place row softmax over 512, then re-mask ----------
__global__ __launch_bounds__(256) void softmax_kernel(float* __restrict__ out,
                                                      const float* __restrict__ mask_lt,
                                                      const float* __restrict__ mask_rt) {
  int lane = threadIdx.x & 63, wave = threadIdx.x >> 6;
  int row = (int)blockIdx.x * 4 + wave;  // 0..32767
  int b = row >> 9;
  float* p = out + (size_t)row * L_;
  float4 v0 = *(const float4*)(p + lane * 8);
  float4 v1 = *(const float4*)(p + lane * 8 + 4);
  float m = fmaxf(fmaxf(fmaxf(v0.x, v0.y), fmaxf(v0.z, v0.w)),
                  fmaxf(fmaxf(v1.x, v1.y), fmaxf(v1.z, v1.w)));
#pragma unroll
  for (int off = 32; off; off >>= 1) m = fmaxf(m, __shfl_xor(m, off));
  float e0 = __expf(v0.x - m), e1 = __expf(v0.y - m), e2 = __expf(v0.z - m), e3 = __expf(v0.w - m);
  float e4 = __expf(v1.x - m), e5 = __expf(v1.y - m), e6 = __expf(v1.z - m), e7 = __expf(v1.w - m);
  float s = ((e0 + e1) + (e2 + e3)) + ((e4 + e5) + (e6 + e7));
#pragma unroll
  for (int off = 32; off; off >>= 1) s += __shfl_xor(s, off);
  float sc = (1.0f / s) * mask_lt[row];
  const float* mrp = mask_rt + (b << 9) + lane * 8;
  float4 mr0 = *(const float4*)mrp;
  float4 mr1 = *(const float4*)(mrp + 4);
  float4 o0 = make_float4(e0 * sc * mr0.x, e1 * sc * mr0.y, e2 * sc * mr0.z, e3 * sc * mr0.w);
  float4 o1 = make_float4(e4 * sc * mr1.x, e5 * sc * mr1.y, e6 * sc * mr1.z, e7 * sc * mr1.w);
  *(float4*)(p + lane * 8) = o0;
  *(float4*)(p + lane * 8 + 4) = o1;
}

extern "C" void kernel_launch(void* const* d_in, const int* in_sizes, int n_in,
                              void* d_out, int out_size, void* d_ws, size_t ws_size,
                              hipStream_t stream) {
  const float* reps_lt = (const float*)d_in[0];
  const float* reps_rt = (const float*)d_in[1];
  const float* mask_lt = (const float*)d_in[2];
  const float* mask_rt = (const float*)d_in[3];
  const float* attn_w1 = (const float*)d_in[4];
  const float* diag    = (const float*)d_in[5];
  float* out = (float*)d_out;

  unsigned short* wt  = (unsigned short*)d_ws;          // 2 MB
  unsigned short* pb  = wt + (size_t)H_ * A_;           // 128 MB
  unsigned short* xb  = pb + (size_t)B_ * L_ * A_ * 2;  // 128 MB
  unsigned short* plt = pb;
  unsigned short* prt = pb + (size_t)B_ * L_ * A_;

  hipLaunchKernelGGL(wtrans_kernel, dim3(1024), dim3(256), 0, stream, attn_w1, wt);
  hipLaunchKernelGGL(cvt_kernel, dim3(8192), dim3(256), 0, stream,
                     reps_lt, reps_rt, xb);
  hipLaunchKernelGGL(proj8_kernel, dim3(2048), dim3(512), 0, stream,
                     xb, wt, diag, pb);
  hipLaunchKernelGGL(score_kernel, dim3(1024), dim3(256), 0, stream,
                     plt, prt, mask_lt, mask_rt, out);
  hipLaunchKernelGGL(softmax_kernel, dim3(8192), dim3(256), 0, stream,
                     out, mask_lt, mask_rt);
}

// Round 10
// 315.271 us; speedup vs baseline: 3.3008x; 1.0154x over previous
//
#include <hip/hip_runtime.h>
#include <hip/hip_bf16.h>

#define B_ 64
#define L_ 512
#define H_ 1024
#define A_ 1024

typedef short bf16x8 __attribute__((ext_vector_type(8)));
typedef float f32x4 __attribute__((ext_vector_type(4)));

__device__ __forceinline__ void gld16(const void* g, void* l) {
  __builtin_amdgcn_global_load_lds((const __attribute__((address_space(1))) void*)g,
                                   (__attribute__((address_space(3))) void*)l, 16, 0, 0);
}

__device__ __forceinline__ unsigned short f2bf(float f) {
  unsigned u = __builtin_bit_cast(unsigned, f);
  u = (u + 0x7fffu + ((u >> 16) & 1u)) >> 16;
  return (unsigned short)u;
}

__device__ __forceinline__ unsigned short cvtbf(float f) {
  __hip_bfloat16 b = __float2bfloat16(f);
  return __builtin_bit_cast(unsigned short, b);
}

__device__ __forceinline__ float fast_tanh(float x) {
  float e = __expf(2.f * x);
  float r = __builtin_amdgcn_rcpf(e + 1.f);
  return __builtin_fmaf(-2.f, r, 1.f);
}

// ---------- K-1: Xb = bf16(concat(Xlt, Xrt)), streaming ----------
__global__ __launch_bounds__(256) void cvt_kernel(const float* __restrict__ lt,
                                                  const float* __restrict__ rt,
                                                  unsigned short* __restrict__ xb) {
  const size_t NC = (size_t)B_ * L_ * H_ / 8;
  size_t stride = (size_t)gridDim.x * blockDim.x;
  for (size_t c = (size_t)blockIdx.x * blockDim.x + threadIdx.x; c < 2 * NC; c += stride) {
    const float* src = (c < NC) ? (lt + c * 8) : (rt + (c - NC) * 8);
    float4 v0 = ((const float4*)src)[0];
    float4 v1 = ((const float4*)src)[1];
    bf16x8 o;
    o[0] = (short)cvtbf(v0.x); o[1] = (short)cvtbf(v0.y);
    o[2] = (short)cvtbf(v0.z); o[3] = (short)cvtbf(v0.w);
    o[4] = (short)cvtbf(v1.x); o[5] = (short)cvtbf(v1.y);
    o[6] = (short)cvtbf(v1.z); o[7] = (short)cvtbf(v1.w);
    *(bf16x8*)(xb + c * 8) = o;
  }
}

// ---------- K0: Wt[a][h] = bf16(W[h][a]) ----------
__global__ __launch_bounds__(256) void wtrans_kernel(const float* __restrict__ W,
                                                     unsigned short* __restrict__ Wt) {
  __shared__ float tile[32][33];
  int tx = threadIdx.x & 31, ty = threadIdx.x >> 5;
  int a0 = (blockIdx.x & 31) << 5, h0 = (blockIdx.x >> 5) << 5;
#pragma unroll
  for (int i = 0; i < 4; ++i) {
    int h = ty + i * 8;
    tile[h][tx] = W[(size_t)(h0 + h) * A_ + a0 + tx];
  }
  __syncthreads();
#pragma unroll
  for (int i = 0; i < 4; ++i) {
    int a = ty + i * 8;
    Wt[(size_t)(a0 + a) * H_ + h0 + tx] = f2bf(tile[tx][a]);
  }
}

// ---------- K1: 256x256 8-phase proj (m201 template): ----------
// Pb = bf16(tanh(Xb @ Wt^T) [*diag]). 512 thr = 8 waves (2M x 4N), BK=64,
// 2 K-tiles/iter, LDS 128KB dbuf. Per phase: {4 ds_read (A-quadrant) ||
// stage 1 half-tile (2 gld16) -> barrier -> 16 MFMA (setprio) -> barrier}.
// B-frags (8 ds_read) once per K-tile. vmcnt(4) ONLY inside phases 4 & 8,
// before the closing barrier (per-wave confirm + barrier publish).
// Conveyor at iter i: ph0,1: A(2i+1)->buf1 | ph2,3: B(2i+2)->buf0 |
// ph4,5: A(2i+2)->buf0 | ph6,7: B(2i+3)->buf1. All writes hit regions whose
// last reader drained >=2 barriers earlier. Last iter wraps kt&15 (dead junk).
__global__ __launch_bounds__(512, 2) void proj8_kernel(
    const unsigned short* __restrict__ Xb, const unsigned short* __restrict__ Wt,
    const float* __restrict__ diag, unsigned short* __restrict__ Pb) {
  __shared__ unsigned short As[2][256 * 64];  // 2 x 32 KB
  __shared__ unsigned short Bs[2][256 * 64];  // 2 x 32 KB
  int t = threadIdx.x;
  int lane = t & 63, wave = t >> 6;
  int wr = wave >> 2, wc = wave & 3;   // 2M x 4N, per-wave 128x64 out
  int l15 = lane & 15, l4 = lane >> 4;

  // XCD swizzle: 4 consecutive N-tiles of one M-tile per XCD slot
  int bid = (int)blockIdx.x;           // 1024 blocks
  int x = bid & 7, k = bid >> 3;
  int mt = x + 8 * (k >> 2);           // [0,256)
  int nt = k & 3;
  int mrow0 = mt << 8, ncol0 = nt << 8;
  int isLt = (mt < 128);

  // staging: thread t covers chunks (row rs, slot ss) and (row rs+64, slot ss)
  // of each 128x64 half-tile; source pre-swizzled slot = ss ^ (rs&7).
  int rs = t >> 3, ss = t & 7;
  const unsigned short* gA = Xb + (size_t)(mrow0 + rs) * H_ + ((ss ^ (rs & 7)) << 3);
  const unsigned short* gB = Wt + (size_t)(ncol0 + rs) * H_ + ((ss ^ (rs & 7)) << 3);
  int lofs = (rs * 8 + ss) * 8;

#define STG_A(buf, h, kt_) {                                              \
    const unsigned short* g_ = gA + (size_t)(h) * 128 * H_ + (kt_) * 64;  \
    gld16(g_, &As[buf][(h) * 8192 + lofs]);                               \
    gld16(g_ + (size_t)64 * H_, &As[buf][(h) * 8192 + 4096 + lofs]); }
#define STG_B(buf, h, kt_) {                                              \
    const unsigned short* g_ = gB + (size_t)(h) * 128 * H_ + (kt_) * 64;  \
    gld16(g_, &Bs[buf][(h) * 8192 + lofs]);                               \
    gld16(g_ + (size_t)64 * H_, &Bs[buf][(h) * 8192 + 4096 + lofs]); }

  int rd0 = (l4 ^ (l15 & 7)) * 8;        // k-slice 0 read slot
  int rd1 = ((4 + l4) ^ (l15 & 7)) * 8;  // k-slice 1

  f32x4 acc[8][4] = {};
  bf16x8 bq[4][2];

#define LOAD_BQ(buf) { _Pragma("unroll") for (int ni = 0; ni < 4; ++ni) {  \
    int brow = wc * 64 + ni * 16 + l15;                                    \
    bq[ni][0] = *(const bf16x8*)&Bs[buf][brow * 64 + rd0];                 \
    bq[ni][1] = *(const bf16x8*)&Bs[buf][brow * 64 + rd1]; } }

#define PHASE(q, buf, STAGE_OP, CKPT) {                                    \
    bf16x8 aq0, aq1, aq2, aq3;                                             \
    { int ar = wr * 128 + (q) * 32 + l15;                                  \
      aq0 = *(const bf16x8*)&As[buf][ar * 64 + rd0];                       \
      aq1 = *(const bf16x8*)&As[buf][ar * 64 + rd1];                       \
      aq2 = *(const bf16x8*)&As[buf][(ar + 16) * 64 + rd0];                \
      aq3 = *(const bf16x8*)&As[buf][(ar + 16) * 64 + rd1]; }              \
    STAGE_OP;                                                              \
    asm volatile("s_barrier" ::: "memory");                                \
    __builtin_amdgcn_s_setprio(1);                                         \
    _Pragma("unroll") for (int ni = 0; ni < 4; ++ni) {                     \
      acc[(q)*2][ni] = __builtin_amdgcn_mfma_f32_16x16x32_bf16(            \
          aq0, bq[ni][0], acc[(q)*2][ni], 0, 0, 0);                        \
      acc[(q)*2][ni] = __builtin_amdgcn_mfma_f32_16x16x32_bf16(            \
          aq1, bq[ni][1], acc[(q)*2][ni], 0, 0, 0);                        \
      acc[(q)*2+1][ni] = __builtin_amdgcn_mfma_f32_16x16x32_bf16(          \
          aq2, bq[ni][0], acc[(q)*2+1][ni], 0, 0, 0);                      \
      acc[(q)*2+1][ni] = __builtin_amdgcn_mfma_f32_16x16x32_bf16(          \
          aq3, bq[ni][1], acc[(q)*2+1][ni], 0, 0, 0); }                    \
    __builtin_amdgcn_s_setprio(0);                                         \
    if (CKPT) asm volatile("s_waitcnt vmcnt(4)" ::: "memory");             \
    asm volatile("s_barrier" ::: "memory"); }

  // prologue: kt0 full -> buf0 (8 loads), kt1 B -> buf1 (4 loads)
  STG_B(0, 0, 0); STG_B(0, 1, 0);
  STG_A(0, 0, 0); STG_A(0, 1, 0);
  STG_B(1, 0, 1); STG_B(1, 1, 1);
  asm volatile("s_waitcnt vmcnt(4)" ::: "memory");  // kt0's 8 done
  asm volatile("s_barrier" ::: "memory");

  for (int i = 0; i < 8; ++i) {
    int kt1 = 2 * i + 1;
    int kt2 = (2 * i + 2) & 15, kt3 = (2 * i + 3) & 15;
    LOAD_BQ(0);
    PHASE(0, 0, STG_A(1, 0, kt1), 0);
    PHASE(1, 0, STG_A(1, 1, kt1), 0);
    PHASE(2, 0, STG_B(0, 0, kt2), 0);
    PHASE(3, 0, STG_B(0, 1, kt2), 1);   // ckpt: buf1 (kt1) published
    LOAD_BQ(1);
    PHASE(0, 1, STG_A(0, 0, kt2), 0);
    PHASE(1, 1, STG_A(0, 1, kt2), 0);
    PHASE(2, 1, STG_B(1, 0, kt3), 0);
    PHASE(3, 1, STG_B(1, 1, kt3), 1);   // ckpt: buf0 (kt0+2) published
  }
#undef PHASE
#undef LOAD_BQ
#undef STG_A
#undef STG_B

#pragma unroll
  for (int mi = 0; mi < 8; ++mi) {
#pragma unroll
    for (int ni = 0; ni < 4; ++ni) {
      int col = ncol0 + wc * 64 + ni * 16 + l15;
      float d = isLt ? diag[col] : 1.0f;
#pragma unroll
      for (int rr = 0; rr < 4; ++rr) {
        int row = mrow0 + wr * 128 + mi * 16 + l4 * 4 + rr;
        Pb[(size_t)row * A_ + col] = f2bf(fast_tanh(acc[mi][ni][rr]) * d);
      }
    }
  }
}

// ---------- K2: scores[b][l][r] = (Plt[b,l,:] . Prt[b,r,:]) * ml * mr ----------
__global__ __launch_bounds__(256) void score_kernel(
    const unsigned short* __restrict__ Plt, const unsigned short* __restrict__ Prt,
    const float* __restrict__ mask_lt, const float* __restrict__ mask_rt,
    float* __restrict__ out) {
  __shared__ unsigned short As[128 * 64];
  __shared__ unsigned short Bs[128 * 64];
  int t = threadIdx.x;
  int lane = t & 63, wave = t >> 6;
  int wr = wave >> 1, wc = wave & 1;
  int l15 = lane & 15, l4 = lane >> 4;

  int bid = (int)blockIdx.x;                 // 1024 blocks
  int x = bid & 7, k = bid >> 3;
  int atile = x + 8 * (k >> 2);              // [0,256)
  int b = atile >> 2, tm = atile & 3, tn = k & 3;

  const unsigned short* Abase = Plt + (size_t)b * L_ * A_ + (size_t)(tm * 128) * A_;
  const unsigned short* Bbase = Prt + (size_t)b * L_ * A_ + (size_t)(tn * 128) * A_;

  const unsigned short* asrc[4];
  const unsigned short* bsrc[4];
  int dst[4];
#pragma unroll
  for (int i = 0; i < 4; ++i) {
    int c = i * 256 + t;
    int r = c >> 3, kc = c & 7;
    int sc = (kc ^ (r & 7)) * 8;
    asrc[i] = &Abase[(size_t)r * A_ + sc];
    bsrc[i] = &Bbase[(size_t)r * A_ + sc];
    dst[i] = c * 8;
  }
  int swz0 = ((0 * 4 + l4) ^ (l15 & 7)) * 8;
  int swz1 = ((1 * 4 + l4) ^ (l15 & 7)) * 8;

  f32x4 acc[4][4] = {};
  for (int kt = 0; kt < A_ / 64; ++kt) {
    int k0 = kt * 64;
    __syncthreads();
#pragma unroll
    for (int i = 0; i < 4; ++i) {
      gld16(asrc[i] + k0, &As[dst[i]]);
      gld16(bsrc[i] + k0, &Bs[dst[i]]);
    }
    __syncthreads();
#pragma unroll
    for (int kk = 0; kk < 2; ++kk) {
      int sw = kk ? swz1 : swz0;
      bf16x8 aq[4], bq[4];
#pragma unroll
      for (int mi = 0; mi < 4; ++mi)
        aq[mi] = *(const bf16x8*)&As[(wr * 64 + mi * 16 + l15) * 64 + sw];
#pragma unroll
      for (int ni = 0; ni < 4; ++ni)
        bq[ni] = *(const bf16x8*)&Bs[(wc * 64 + ni * 16 + l15) * 64 + sw];
#pragma unroll
      for (int mi = 0; mi < 4; ++mi)
#pragma unroll
        for (int ni = 0; ni < 4; ++ni)
          acc[mi][ni] = __builtin_amdgcn_mfma_f32_16x16x32_bf16(aq[mi], bq[ni], acc[mi][ni], 0, 0, 0);
    }
  }
  const float* mlp = mask_lt + b * L_;
  const float* mrp = mask_rt + b * L_;
  float* obase = out + (size_t)b * L_ * L_;
#pragma unroll
  for (int mi = 0; mi < 4; ++mi) {
#pragma unroll
    for (int ni = 0; ni < 4; ++ni) {
      int col = tn * 128 + wc * 64 + ni * 16 + l15;
      float mr = mrp[col];
#pragma unroll
      for (int r = 0; r < 4; ++r) {
        int row = tm * 128 + wr * 64 + mi * 16 + l4 * 4 + r;
        obase[(size_t)row * L_ + col] = acc[mi][ni][r] * mlp[row] * mr;
      }
    }
  }
}

// ---------- K3: in-place row softmax over 512, then re-mask ----------
__global__ __launch_bounds__(256) void softmax_kernel(float* __restrict__ out,
                                                      const float* __restrict__ mask_lt,
                                                      const float* __restrict__ mask_rt) {
  int lane = threadIdx.x & 63, wave = threadIdx.x >> 6;
  int row = (int)blockIdx.x * 4 + wave;
  int b = row >> 9;
  float* p = out + (size_t)row * L_;
  float4 v0 = *(const float4*)(p + lane * 8);
  float4 v1 = *(const float4*)(p + lane * 8 + 4);
  float m = fmaxf(fmaxf(fmaxf(v0.x, v0.y), fmaxf(v0.z, v0.w)),
                  fmaxf(fmaxf(v1.x, v1.y), fmaxf(v1.z, v1.w)));
#pragma unroll
  for (int off = 32; off; off >>= 1) m = fmaxf(m, __shfl_xor(m, off));
  float e0 = __expf(v0.x - m), e1 = __expf(v0.y - m), e2 = __expf(v0.z - m), e3 = __expf(v0.w - m);
  float e4 = __expf(v1.x - m), e5 = __expf(v1.y - m), e6 = __expf(v1.z - m), e7 = __expf(v1.w - m);
  float s = ((e0 + e1) + (e2 + e3)) + ((e4 + e5) + (e6 + e7));
#pragma unroll
  for (int off = 32; off; off >>= 1) s += __shfl_xor(s, off);
  float sc = (1.0f / s) * mask_lt[row];
  const float* mrp = mask_rt + (b << 9) + lane * 8;
  float4 mr0 = *(const float4*)mrp;
  float4 mr1 = *(const float4*)(mrp + 4);
  float4 o0 = make_float4(e0 * sc * mr0.x, e1 * sc * mr0.y, e2 * sc * mr0.z, e3 * sc * mr0.w);
  float4 o1 = make_float4(e4 * sc * mr1.x, e5 * sc * mr1.y, e6 * sc * mr1.z, e7 * sc * mr1.w);
  *(float4*)(p + lane * 8) = o0;
  *(float4*)(p + lane * 8 + 4) = o1;
}

extern "C" void kernel_launch(void* const* d_in, const int* in_sizes, int n_in,
                              void* d_out, int out_size, void* d_ws, size_t ws_size,
                              hipStream_t stream) {
  const float* reps_lt = (const float*)d_in[0];
  const float* reps_rt = (const float*)d_in[1];
  const float* mask_lt = (const float*)d_in[2];
  const float* mask_rt = (const float*)d_in[3];
  const float* attn_w1 = (const float*)d_in[4];
  const float* diag    = (const float*)d_in[5];
  float* out = (float*)d_out;

  unsigned short* wt  = (unsigned short*)d_ws;          // 2 MB
  unsigned short* pb  = wt + (size_t)H_ * A_;           // 128 MB
  unsigned short* xb  = pb + (size_t)B_ * L_ * A_ * 2;  // 128 MB
  unsigned short* plt = pb;
  unsigned short* prt = pb + (size_t)B_ * L_ * A_;

  hipLaunchKernelGGL(wtrans_kernel, dim3(1024), dim3(256), 0, stream, attn_w1, wt);
  hipLaunchKernelGGL(cvt_kernel, dim3(8192), dim3(256), 0, stream,
                     reps_lt, reps_rt, xb);
  hipLaunchKernelGGL(proj8_kernel, dim3(1024), dim3(512), 0, stream,
                     xb, wt, diag, pb);
  hipLaunchKernelGGL(score_kernel, dim3(1024), dim3(256), 0, stream,
                     plt, prt, mask_lt, mask_rt, out);
  hipLaunchKernelGGL(softmax_kernel, dim3(8192), dim3(256), 0, stream,
                     out, mask_lt, mask_rt);
}

// Round 11
// 299.267 us; speedup vs baseline: 3.4773x; 1.0535x over previous
//
#include <hip/hip_runtime.h>
#include <hip/hip_bf16.h>

#define B_ 64
#define L_ 512
#define H_ 1024
#define A_ 1024

typedef short bf16x8 __attribute__((ext_vector_type(8)));
typedef float f32x4 __attribute__((ext_vector_type(4)));

__device__ __forceinline__ void gld16(const void* g, void* l) {
  __builtin_amdgcn_global_load_lds((const __attribute__((address_space(1))) void*)g,
                                   (__attribute__((address_space(3))) void*)l, 16, 0, 0);
}

__device__ __forceinline__ unsigned short f2bf(float f) {
  unsigned u = __builtin_bit_cast(unsigned, f);
  u = (u + 0x7fffu + ((u >> 16) & 1u)) >> 16;
  return (unsigned short)u;
}

__device__ __forceinline__ unsigned short cvtbf(float f) {
  __hip_bfloat16 b = __float2bfloat16(f);
  return __builtin_bit_cast(unsigned short, b);
}

__device__ __forceinline__ float fast_tanh(float x) {
  float e = __expf(2.f * x);
  float r = __builtin_amdgcn_rcpf(e + 1.f);
  return __builtin_fmaf(-2.f, r, 1.f);
}

// ---------- K-1: Xb = bf16(concat(Xlt, Xrt)), streaming ----------
__global__ __launch_bounds__(256) void cvt_kernel(const float* __restrict__ lt,
                                                  const float* __restrict__ rt,
                                                  unsigned short* __restrict__ xb) {
  const size_t NC = (size_t)B_ * L_ * H_ / 8;
  size_t stride = (size_t)gridDim.x * blockDim.x;
  for (size_t c = (size_t)blockIdx.x * blockDim.x + threadIdx.x; c < 2 * NC; c += stride) {
    const float* src = (c < NC) ? (lt + c * 8) : (rt + (c - NC) * 8);
    float4 v0 = ((const float4*)src)[0];
    float4 v1 = ((const float4*)src)[1];
    bf16x8 o;
    o[0] = (short)cvtbf(v0.x); o[1] = (short)cvtbf(v0.y);
    o[2] = (short)cvtbf(v0.z); o[3] = (short)cvtbf(v0.w);
    o[4] = (short)cvtbf(v1.x); o[5] = (short)cvtbf(v1.y);
    o[6] = (short)cvtbf(v1.z); o[7] = (short)cvtbf(v1.w);
    *(bf16x8*)(xb + c * 8) = o;
  }
}

// ---------- K0: Wt[a][h] = bf16(W[h][a]) ----------
__global__ __launch_bounds__(256) void wtrans_kernel(const float* __restrict__ W,
                                                     unsigned short* __restrict__ Wt) {
  __shared__ float tile[32][33];
  int tx = threadIdx.x & 31, ty = threadIdx.x >> 5;
  int a0 = (blockIdx.x & 31) << 5, h0 = (blockIdx.x >> 5) << 5;
#pragma unroll
  for (int i = 0; i < 4; ++i) {
    int h = ty + i * 8;
    tile[h][tx] = W[(size_t)(h0 + h) * A_ + a0 + tx];
  }
  __syncthreads();
#pragma unroll
  for (int i = 0; i < 4; ++i) {
    int a = ty + i * 8;
    Wt[(size_t)(a0 + a) * H_ + h0 + tx] = f2bf(tile[tx][a]);
  }
}

// ================= shared 8-phase conveyor macros (m201 template) =========
// 512 thr = 8 waves (2M x 4N), 256x256 tile, BK=64, 2 K-tiles/iter,
// LDS 2x32KB per operand. vmcnt(4) checkpoints only at phases 4 & 8.
#define STG_FROM(gptr, Ls, buf, h, kt_) {                                  \
    const unsigned short* g_ = (gptr) + (size_t)(h) * 128 * H_ + (kt_) * 64; \
    gld16(g_, &Ls[buf][(h) * 8192 + lofs]);                                \
    gld16(g_ + (size_t)64 * H_, &Ls[buf][(h) * 8192 + 4096 + lofs]); }

#define LOAD_BQ(Bsrc, buf) { _Pragma("unroll") for (int ni = 0; ni < 4; ++ni) { \
    int brow = wc * 64 + ni * 16 + l15;                                    \
    bq[ni][0] = *(const bf16x8*)&Bsrc[buf][brow * 64 + rd0];               \
    bq[ni][1] = *(const bf16x8*)&Bsrc[buf][brow * 64 + rd1]; } }

#define PHASE(Asrc, q, buf, STAGE_OP, CKPT) {                              \
    bf16x8 aq0, aq1, aq2, aq3;                                             \
    { int ar = wr * 128 + (q) * 32 + l15;                                  \
      aq0 = *(const bf16x8*)&Asrc[buf][ar * 64 + rd0];                     \
      aq1 = *(const bf16x8*)&Asrc[buf][ar * 64 + rd1];                     \
      aq2 = *(const bf16x8*)&Asrc[buf][(ar + 16) * 64 + rd0];              \
      aq3 = *(const bf16x8*)&Asrc[buf][(ar + 16) * 64 + rd1]; }            \
    STAGE_OP;                                                              \
    asm volatile("s_barrier" ::: "memory");                                \
    __builtin_amdgcn_s_setprio(1);                                         \
    _Pragma("unroll") for (int ni = 0; ni < 4; ++ni) {                     \
      acc[(q)*2][ni] = __builtin_amdgcn_mfma_f32_16x16x32_bf16(            \
          aq0, bq[ni][0], acc[(q)*2][ni], 0, 0, 0);                        \
      acc[(q)*2][ni] = __builtin_amdgcn_mfma_f32_16x16x32_bf16(            \
          aq1, bq[ni][1], acc[(q)*2][ni], 0, 0, 0);                        \
      acc[(q)*2+1][ni] = __builtin_amdgcn_mfma_f32_16x16x32_bf16(          \
          aq2, bq[ni][0], acc[(q)*2+1][ni], 0, 0, 0);                      \
      acc[(q)*2+1][ni] = __builtin_amdgcn_mfma_f32_16x16x32_bf16(          \
          aq3, bq[ni][1], acc[(q)*2+1][ni], 0, 0, 0); }                    \
    __builtin_amdgcn_s_setprio(0);                                         \
    if (CKPT) asm volatile("s_waitcnt vmcnt(4)" ::: "memory");             \
    asm volatile("s_barrier" ::: "memory"); }

// Conveyor body (16 K-tiles): prologue stages kt0 full->buf0, kt1-B->buf1.
// Iter i: LOAD_BQ(0); A(2i+1)->buf1 x2; B(2i+2)->buf0 x2 [ckpt];
//         LOAD_BQ(1); A(2i+2)->buf0 x2; B(2i+3)->buf1 x2 [ckpt].
#define CONVEYOR(gA_, gB_)                                                 \
  STG_FROM(gB_, Bs, 0, 0, 0); STG_FROM(gB_, Bs, 0, 1, 0);                  \
  STG_FROM(gA_, As, 0, 0, 0); STG_FROM(gA_, As, 0, 1, 0);                  \
  STG_FROM(gB_, Bs, 1, 0, 1); STG_FROM(gB_, Bs, 1, 1, 1);                  \
  asm volatile("s_waitcnt vmcnt(4)" ::: "memory");                         \
  asm volatile("s_barrier" ::: "memory");                                  \
  for (int i = 0; i < 8; ++i) {                                            \
    int kt1 = 2 * i + 1;                                                   \
    int kt2 = (2 * i + 2) & 15, kt3 = (2 * i + 3) & 15;                    \
    LOAD_BQ(Bs, 0);                                                        \
    PHASE(As, 0, 0, STG_FROM(gA_, As, 1, 0, kt1), 0);                      \
    PHASE(As, 1, 0, STG_FROM(gA_, As, 1, 1, kt1), 0);                      \
    PHASE(As, 2, 0, STG_FROM(gB_, Bs, 0, 0, kt2), 0);                      \
    PHASE(As, 3, 0, STG_FROM(gB_, Bs, 0, 1, kt2), 1);                      \
    LOAD_BQ(Bs, 1);                                                        \
    PHASE(As, 0, 1, STG_FROM(gA_, As, 0, 0, kt2), 0);                      \
    PHASE(As, 1, 1, STG_FROM(gA_, As, 0, 1, kt2), 0);                      \
    PHASE(As, 2, 1, STG_FROM(gB_, Bs, 1, 0, kt3), 0);                      \
    PHASE(As, 3, 1, STG_FROM(gB_, Bs, 1, 1, kt3), 1);                      \
  }

// ---------- K1: 256x256 8-phase proj: Pb = bf16(tanh(Xb@Wt^T)[*diag]) ------
__global__ __launch_bounds__(512, 2) void proj8_kernel(
    const unsigned short* __restrict__ Xb, const unsigned short* __restrict__ Wt,
    const float* __restrict__ diag, unsigned short* __restrict__ Pb) {
  __shared__ unsigned short As[2][256 * 64];
  __shared__ unsigned short Bs[2][256 * 64];
  int t = threadIdx.x;
  int lane = t & 63, wave = t >> 6;
  int wr = wave >> 2, wc = wave & 3;
  int l15 = lane & 15, l4 = lane >> 4;

  int bid = (int)blockIdx.x;           // 1024 blocks
  int x = bid & 7, k = bid >> 3;
  int mt = x + 8 * (k >> 2);           // [0,256)
  int nt = k & 3;
  int mrow0 = mt << 8, ncol0 = nt << 8;
  int isLt = (mt < 128);

  int rs = t >> 3, ss = t & 7;
  const unsigned short* gA = Xb + (size_t)(mrow0 + rs) * H_ + ((ss ^ (rs & 7)) << 3);
  const unsigned short* gB = Wt + (size_t)(ncol0 + rs) * H_ + ((ss ^ (rs & 7)) << 3);
  int lofs = (rs * 8 + ss) * 8;

  int rd0 = (l4 ^ (l15 & 7)) * 8;
  int rd1 = ((4 + l4) ^ (l15 & 7)) * 8;

  f32x4 acc[8][4] = {};
  bf16x8 bq[4][2];

  CONVEYOR(gA, gB);

#pragma unroll
  for (int mi = 0; mi < 8; ++mi) {
#pragma unroll
    for (int ni = 0; ni < 4; ++ni) {
      int col = ncol0 + wc * 64 + ni * 16 + l15;
      float d = isLt ? diag[col] : 1.0f;
#pragma unroll
      for (int rr = 0; rr < 4; ++rr) {
        int row = mrow0 + wr * 128 + mi * 16 + l4 * 4 + rr;
        Pb[(size_t)row * A_ + col] = f2bf(fast_tanh(acc[mi][ni][rr]) * d);
      }
    }
  }
}

// ---------- K2: 8-phase score: out[b][l][r] = (Plt.Prt^T) * ml * mr ----------
// Same conveyor; per batch 2x2 tiles of 256^2 -> 256 blocks (1 per CU).
__global__ __launch_bounds__(512, 2) void score8_kernel(
    const unsigned short* __restrict__ Pb,
    const float* __restrict__ mask_lt, const float* __restrict__ mask_rt,
    float* __restrict__ out) {
  __shared__ unsigned short As[2][256 * 64];
  __shared__ unsigned short Bs[2][256 * 64];
  int t = threadIdx.x;
  int lane = t & 63, wave = t >> 6;
  int wr = wave >> 2, wc = wave & 3;
  int l15 = lane & 15, l4 = lane >> 4;

  // 256 blocks: x = bid&7, k = bid>>3 in [0,32); (b,mt) = x+8*(k>>1), tn = k&1
  int bid = (int)blockIdx.x;
  int x = bid & 7, k = bid >> 3;
  int pm = x + 8 * (k >> 1);           // [0,128)
  int b = pm >> 1, mt = pm & 1, nt = k & 1;

  int arow0 = b * 512 + mt * 256;            // Plt rows
  int brow0 = 32768 + b * 512 + nt * 256;    // Prt rows

  int rs = t >> 3, ss = t & 7;
  const unsigned short* gA = Pb + (size_t)(arow0 + rs) * H_ + ((ss ^ (rs & 7)) << 3);
  const unsigned short* gB = Pb + (size_t)(brow0 + rs) * H_ + ((ss ^ (rs & 7)) << 3);
  int lofs = (rs * 8 + ss) * 8;

  int rd0 = (l4 ^ (l15 & 7)) * 8;
  int rd1 = ((4 + l4) ^ (l15 & 7)) * 8;

  f32x4 acc[8][4] = {};
  bf16x8 bq[4][2];

  CONVEYOR(gA, gB);

  const float* mlp = mask_lt + b * L_;
  const float* mrp = mask_rt + b * L_;
  float* obase = out + (size_t)b * L_ * L_;
#pragma unroll
  for (int mi = 0; mi < 8; ++mi) {
#pragma unroll
    for (int ni = 0; ni < 4; ++ni) {
      int col = nt * 256 + wc * 64 + ni * 16 + l15;
      float mr = mrp[col];
#pragma unroll
      for (int rr = 0; rr < 4; ++rr) {
        int row = mt * 256 + wr * 128 + mi * 16 + l4 * 4 + rr;
        obase[(size_t)row * L_ + col] = acc[mi][ni][rr] * mlp[row] * mr;
      }
    }
  }
}

// ---------- K3: in-place row softmax over 512, then re-mask ----------
__global__ __launch_bounds__(256) void softmax_kernel(float* __restrict__ out,
                                                      const float* __restrict__ mask_lt,
                                                      const float* __restrict__ mask_rt) {
  int lane = threadIdx.x & 63, wave = threadIdx.x >> 6;
  int row = (int)blockIdx.x * 4 + wave;
  int b = row >> 9;
  float* p = out + (size_t)row * L_;
  float4 v0 = *(const float4*)(p + lane * 8);
  float4 v1 = *(const float4*)(p + lane * 8 + 4);
  float m = fmaxf(fmaxf(fmaxf(v0.x, v0.y), fmaxf(v0.z, v0.w)),
                  fmaxf(fmaxf(v1.x, v1.y), fmaxf(v1.z, v1.w)));
#pragma unroll
  for (int off = 32; off; off >>= 1) m = fmaxf(m, __shfl_xor(m, off));
  float e0 = __expf(v0.x - m), e1 = __expf(v0.y - m), e2 = __expf(v0.z - m), e3 = __expf(v0.w - m);
  float e4 = __expf(v1.x - m), e5 = __expf(v1.y - m), e6 = __expf(v1.z - m), e7 = __expf(v1.w - m);
  float s = ((e0 + e1) + (e2 + e3)) + ((e4 + e5) + (e6 + e7));
#pragma unroll
  for (int off = 32; off; off >>= 1) s += __shfl_xor(s, off);
  float sc = (1.0f / s) * mask_lt[row];
  const float* mrp = mask_rt + (b << 9) + lane * 8;
  float4 mr0 = *(const float4*)mrp;
  float4 mr1 = *(const float4*)(mrp + 4);
  float4 o0 = make_float4(e0 * sc * mr0.x, e1 * sc * mr0.y, e2 * sc * mr0.z, e3 * sc * mr0.w);
  float4 o1 = make_float4(e4 * sc * mr1.x, e5 * sc * mr1.y, e6 * sc * mr1.z, e7 * sc * mr1.w);
  *(float4*)(p + lane * 8) = o0;
  *(float4*)(p + lane * 8 + 4) = o1;
}

extern "C" void kernel_launch(void* const* d_in, const int* in_sizes, int n_in,
                              void* d_out, int out_size, void* d_ws, size_t ws_size,
                              hipStream_t stream) {
  const float* reps_lt = (const float*)d_in[0];
  const float* reps_rt = (const float*)d_in[1];
  const float* mask_lt = (const float*)d_in[2];
  const float* mask_rt = (const float*)d_in[3];
  const float* attn_w1 = (const float*)d_in[4];
  const float* diag    = (const float*)d_in[5];
  float* out = (float*)d_out;

  unsigned short* wt  = (unsigned short*)d_ws;          // 2 MB
  unsigned short* pb  = wt + (size_t)H_ * A_;           // 128 MB
  unsigned short* xb  = pb + (size_t)B_ * L_ * A_ * 2;  // 128 MB

  hipLaunchKernelGGL(wtrans_kernel, dim3(1024), dim3(256), 0, stream, attn_w1, wt);
  hipLaunchKernelGGL(cvt_kernel, dim3(8192), dim3(256), 0, stream,
                     reps_lt, reps_rt, xb);
  hipLaunchKernelGGL(proj8_kernel, dim3(1024), dim3(512), 0, stream,
                     xb, wt, diag, pb);
  hipLaunchKernelGGL(score8_kernel, dim3(256), dim3(512), 0, stream,
                     pb, mask_lt, mask_rt, out);
  hipLaunchKernelGGL(softmax_kernel, dim3(8192), dim3(256), 0, stream,
                     out, mask_lt, mask_rt);
}